// Round 2
// baseline (41.994 us; speedup 1.0000x reference)
//
#include <hip/hip_runtime.h>

// SegBrightnessLoss: loss = sum_i mean((a2'-d2_i)^2) over the (b,b,h,w)
// broadcast, reduced algebraically to per-class {S_i, C_i} + global SS:
//   d2_i = S_i/N,  d3_i = (SS_i - 2 S_i^2/N + C_i S_i^2/N^2)/N,
//   sum_i SS_i = SS_total (classes partition pixels), N = b*h*w.
// One fused pass over x (50.3 MB) + y (16.8 MB); per-block partials in ws
// (transposed: ws[q*nblocks + b]) -> no pre-zero memset, no atomics.

constexpr int kHW = 512 * 512;           // 262144
constexpr int kB = 16;
constexpr int kNPix = kB * kHW;          // 4194304 = N
constexpr int kNCls = 11;
constexpr int kNQ = 2 * kNCls + 1;       // S[0..10], C[0..10], SS
constexpr int kMaxBlocks = 2048;         // 8 blocks/CU -> 32 waves/CU

__global__ __launch_bounds__(256) void seg_main_kernel(
    const float* __restrict__ x, const int* __restrict__ y,
    double* __restrict__ ws) {
  float s[kNCls];
  float cn[kNCls];
  float ss = 0.f;
#pragma unroll
  for (int i = 0; i < kNCls; ++i) { s[i] = 0.f; cn[i] = 0.f; }

  const int ngroups = kNPix / 4;
  const int stride = gridDim.x * blockDim.x;
  for (int g = blockIdx.x * blockDim.x + threadIdx.x; g < ngroups; g += stride) {
    const int p = g << 2;                 // first pixel of this 4-group
    const int b = p >> 18;                // p / kHW  (kHW = 2^18)
    const int off = p & (kHW - 1);
    const float* xb = x + (size_t)b * 3 * kHW + off;
    const float4 x0 = *reinterpret_cast<const float4*>(xb);
    const float4 x1 = *reinterpret_cast<const float4*>(xb + kHW);
    const float4 x2 = *reinterpret_cast<const float4*>(xb + 2 * kHW);
    const int4 yv = *reinterpret_cast<const int4*>(y + p);

    float xm[4] = {(x0.x + x1.x + x2.x) * (1.f / 3.f),
                   (x0.y + x1.y + x2.y) * (1.f / 3.f),
                   (x0.z + x1.z + x2.z) * (1.f / 3.f),
                   (x0.w + x1.w + x2.w) * (1.f / 3.f)};
    int yy[4] = {yv.x, yv.y, yv.z, yv.w};
#pragma unroll
    for (int j = 0; j < 4; ++j) {
      const float m = xm[j];
      const bool nz = (m != 0.0f);        // exact a2==0 semantics of the ref
      ss += nz ? m * m : 0.f;
#pragma unroll
      for (int i = 0; i < kNCls; ++i) {
        const bool hit = nz && (yy[j] == i);
        s[i] += hit ? m : 0.f;
        cn[i] += hit ? 1.f : 0.f;
      }
    }
  }

  float r[kNQ];
#pragma unroll
  for (int i = 0; i < kNCls; ++i) { r[i] = s[i]; r[kNCls + i] = cn[i]; }
  r[2 * kNCls] = ss;

  // 64-lane wave shuffle reduction
#pragma unroll
  for (int k = 0; k < kNQ; ++k) {
    float v = r[k];
#pragma unroll
    for (int o = 32; o > 0; o >>= 1) v += __shfl_down(v, o, 64);
    r[k] = v;
  }

  __shared__ double part[4][kNQ];
  const int lane = threadIdx.x & 63;
  const int wave = threadIdx.x >> 6;
  if (lane == 0) {
#pragma unroll
    for (int k = 0; k < kNQ; ++k) part[wave][k] = (double)r[k];
  }
  __syncthreads();
  if (threadIdx.x < kNQ) {
    const int q = threadIdx.x;
    // transposed partials: quantity-major so the final kernel reads coalesced
    ws[(size_t)q * gridDim.x + blockIdx.x] =
        part[0][q] + part[1][q] + part[2][q] + part[3][q];
  }
}

__global__ __launch_bounds__(768) void seg_final_kernel(
    const double* __restrict__ ws, float* __restrict__ out, int nblocks) {
  __shared__ double tot[kNQ];
  const int q = threadIdx.x >> 5;         // 32 lanes per quantity
  const int lane = threadIdx.x & 31;
  if (q < kNQ) {
    double v = 0.0;
    for (int j = lane; j < nblocks; j += 32) v += ws[(size_t)q * nblocks + j];
#pragma unroll
    for (int o = 16; o > 0; o >>= 1) v += __shfl_down(v, o, 32);
    if (lane == 0) tot[q] = v;
  }
  __syncthreads();
  if (threadIdx.x == 0) {
    const double N = (double)kNPix;
    double acc = tot[2 * kNCls];          // SS_total
    for (int i = 0; i < kNCls; ++i) {
      const double S = tot[i];
      const double C = tot[kNCls + i];
      acc += S * S * (C / N - 2.0) / N;   // -2 S^2/N + C S^2/N^2
    }
    out[0] = (float)(acc / N);
  }
}

extern "C" void kernel_launch(void* const* d_in, const int* in_sizes, int n_in,
                              void* d_out, int out_size, void* d_ws, size_t ws_size,
                              hipStream_t stream) {
  const float* x = (const float*)d_in[0];
  const int* y = (const int*)d_in[1];
  float* out = (float*)d_out;
  double* ws = (double*)d_ws;

  int nblocks = kMaxBlocks;
  const size_t need = (size_t)kNQ * sizeof(double);
  if (ws_size < (size_t)kMaxBlocks * need) {
    nblocks = (int)(ws_size / need);
    if (nblocks < 1) nblocks = 1;
  }

  seg_main_kernel<<<nblocks, 256, 0, stream>>>(x, y, ws);
  seg_final_kernel<<<1, 768, 0, stream>>>(ws, out, nblocks);
}

// Round 4
// 26.278 us; speedup vs baseline: 1.5981x; 1.5981x over previous
//
#include <hip/hip_runtime.h>

// SegBrightnessLoss, algebraically reduced to per-class {S_i, C_i} + global SS:
//   d2_i = S_i/N,  d3_i = (SS_i - 2 S_i^2/N + C_i S_i^2/N^2)/N,  sum_i SS_i = SS,
//   N = b*h*w = 4194304. One fused pass over x (50.3 MB) + y (16.8 MB int32).
// TWO kernels, no memset, no atomics: per-block partials (plain stores) are
// made visible by the kernel boundary (R2 proved this correct; the fused
// single-kernel threadfence variant raced on cross-XCD L2 in R3).

constexpr int kHW = 512 * 512;            // 262144
constexpr int kB = 16;
constexpr int kNPix = kB * kHW;           // 4194304 = N
constexpr int kNCls = 11;
constexpr int kNQ = 2 * kNCls + 1;        // S[0..10], C[0..10], SS
constexpr int kBlocks = 1024;             // 4 blocks/CU -> 16 waves/CU

__global__ __launch_bounds__(256) void seg_main_kernel(
    const float* __restrict__ x, const int* __restrict__ y,
    double* __restrict__ pd) {
  const int tid = threadIdx.x;
  const int bid = blockIdx.x;

  float s[kNCls], cn[kNCls], ss = 0.f;
#pragma unroll
  for (int i = 0; i < kNCls; ++i) { s[i] = 0.f; cn[i] = 0.f; }

  const int ngroups = kNPix / 4;          // 1048576 float4/int4 groups
  const int stride = kBlocks * 256;       // compile-time stride -> 4 iters
  for (int g = bid * 256 + tid; g < ngroups; g += stride) {
    const int p = g << 2;
    const int b = p >> 18;                // p / kHW  (kHW = 2^18)
    const int off = p & (kHW - 1);
    const float* xb = x + (size_t)b * 3 * kHW + off;
    const float4 x0 = *reinterpret_cast<const float4*>(xb);
    const float4 x1 = *reinterpret_cast<const float4*>(xb + kHW);
    const float4 x2 = *reinterpret_cast<const float4*>(xb + 2 * kHW);
    const int4 yv = *reinterpret_cast<const int4*>(y + p);

    float xm[4] = {(x0.x + x1.x + x2.x) * (1.f / 3.f),
                   (x0.y + x1.y + x2.y) * (1.f / 3.f),
                   (x0.z + x1.z + x2.z) * (1.f / 3.f),
                   (x0.w + x1.w + x2.w) * (1.f / 3.f)};
    int yy[4] = {yv.x, yv.y, yv.z, yv.w};
#pragma unroll
    for (int j = 0; j < 4; ++j) {
      const float m = xm[j];
      const bool nz = (m != 0.0f);        // exact a2==0 semantics of the ref
      ss += nz ? m * m : 0.f;
#pragma unroll
      for (int i = 0; i < kNCls; ++i) {
        const bool hit = nz && (yy[j] == i);
        s[i] += hit ? m : 0.f;
        cn[i] += hit ? 1.f : 0.f;
      }
    }
  }

  float r[kNQ];
#pragma unroll
  for (int i = 0; i < kNCls; ++i) { r[i] = s[i]; r[kNCls + i] = cn[i]; }
  r[2 * kNCls] = ss;

  // 64-lane wave shuffle reduction
#pragma unroll
  for (int k = 0; k < kNQ; ++k) {
    float v = r[k];
#pragma unroll
    for (int o = 32; o > 0; o >>= 1) v += __shfl_down(v, o, 64);
    r[k] = v;
  }

  __shared__ double part[4][kNQ];
  const int lane = tid & 63, wave = tid >> 6;
  if (lane == 0) {
#pragma unroll
    for (int k = 0; k < kNQ; ++k) part[wave][k] = (double)r[k];
  }
  __syncthreads();
  if (tid < kNQ)                          // quantity-major: coalesced finale
    pd[(size_t)tid * kBlocks + bid] =
        part[0][tid] + part[1][tid] + part[2][tid] + part[3][tid];
}

__global__ __launch_bounds__(1024) void seg_final_kernel(
    const double* __restrict__ pd, float* __restrict__ out) {
  __shared__ double tot[kNQ];
  const int q = threadIdx.x >> 5;         // 32 lanes per quantity
  const int lane = threadIdx.x & 31;
  if (q < kNQ) {
    double v = 0.0;
#pragma unroll
    for (int j = 0; j < kBlocks / 32; ++j)   // 32 unrolled independent loads
      v += pd[(size_t)q * kBlocks + lane + 32 * j];
#pragma unroll
    for (int o = 16; o > 0; o >>= 1) v += __shfl_down(v, o, 32);
    if (lane == 0) tot[q] = v;
  }
  __syncthreads();
  if (threadIdx.x == 0) {
    const double N = (double)kNPix;
    double acc = tot[2 * kNCls];          // SS_total
    for (int i = 0; i < kNCls; ++i) {
      const double S = tot[i];
      const double C = tot[kNCls + i];
      acc += S * S * (C / N - 2.0) / N;   // -2 S^2/N + C S^2/N^2
    }
    out[0] = (float)(acc / N);
  }
}

extern "C" void kernel_launch(void* const* d_in, const int* in_sizes, int n_in,
                              void* d_out, int out_size, void* d_ws, size_t ws_size,
                              hipStream_t stream) {
  const float* x = (const float*)d_in[0];
  const int* y = (const int*)d_in[1];
  float* out = (float*)d_out;
  double* pd = (double*)d_ws;             // 23 * 1024 * 8 = 188 KB

  seg_main_kernel<<<kBlocks, 256, 0, stream>>>(x, y, pd);
  seg_final_kernel<<<1, 1024, 0, stream>>>(pd, out);
}

// Round 7
// 21.617 us; speedup vs baseline: 1.9427x; 1.2157x over previous
//
#include <hip/hip_runtime.h>

// SegBrightnessLoss reduced to per-class {S_i, C_i} + global SS:
//   d2_i = S_i/N,  d3_i = (SS_i - 2 S_i^2/N + C_i S_i^2/N^2)/N,  sum_i SS_i = SS,
//   N = 4194304. One fused pass over x (50.3 MB fp32) + y (16.8 MB int32).
// Two kernels (kernel boundary = the only proven cross-XCD sync; R3's fused
// threadfence variant raced). Slim loop: 11 counts packed in one u64
// (5-bit fields), nz folded into cls once, LDS-transpose block epilogue.

constexpr int kHW = 512 * 512;            // 262144
constexpr int kB = 16;
constexpr int kNPix = kB * kHW;           // 4194304 = N
constexpr int kNCls = 11;
constexpr int kNQ = 2 * kNCls + 1;        // q: 0..10 = S_i, 11..21 = C_i, 22 = SS
constexpr int kBlocks = 1024;             // 4 blocks/CU -> 16 waves/CU
constexpr int kThreads = 256;

__global__ __launch_bounds__(256) void seg_main_kernel(
    const float* __restrict__ x, const int* __restrict__ y,
    double* __restrict__ pd) {
  const int tid = threadIdx.x, bid = blockIdx.x;

  float s[kNCls];
#pragma unroll
  for (int i = 0; i < kNCls; ++i) s[i] = 0.f;
  float ss = 0.f;
  // 11 per-class counts in 5-bit fields at bit 5*cls; m==0 pixels go to
  // cls=12 (bits 60..63, harmless garbage). <=16 px/thread -> no field ovfl.
  unsigned long long pack = 0ull;

  constexpr int kStride = kBlocks * kThreads;   // 262144
  constexpr int kIters = (kNPix / 4) / kStride; // 4, exact
#pragma unroll
  for (int it = 0; it < kIters; ++it) {
    const int g = bid * kThreads + tid + it * kStride;
    const int p = g << 2;
    const int b = p >> 18;                // p / kHW  (kHW = 2^18)
    const int off = p & (kHW - 1);
    const float* xb = x + (size_t)b * 3 * kHW + off;
    const float4 x0 = *reinterpret_cast<const float4*>(xb);
    const float4 x1 = *reinterpret_cast<const float4*>(xb + kHW);
    const float4 x2 = *reinterpret_cast<const float4*>(xb + 2 * kHW);
    const int4 yv = *reinterpret_cast<const int4*>(y + p);

    const float xm[4] = {(x0.x + x1.x + x2.x) * (1.f / 3.f),
                         (x0.y + x1.y + x2.y) * (1.f / 3.f),
                         (x0.z + x1.z + x2.z) * (1.f / 3.f),
                         (x0.w + x1.w + x2.w) * (1.f / 3.f)};
    const int yy[4] = {yv.x, yv.y, yv.z, yv.w};
#pragma unroll
    for (int j = 0; j < 4; ++j) {
      const float m = xm[j];
      const bool nz = (m != 0.0f);        // exact a2==0 semantics of the ref
      const float mq = nz ? m : 0.f;
      ss = fmaf(mq, m, ss);               // m^2 iff nz
      const int cls = nz ? yy[j] : 12;    // fold nz into the class id once
      pack += 1ull << (5 * cls);          // all 11 counts in one add
#pragma unroll
      for (int i = 0; i < kNCls; ++i)
        s[i] += (cls == i) ? m : 0.f;     // cmp + cndmask + add
    }
  }

  // ---- block epilogue: LDS transpose, 8 lanes per quantity ----
  float qv[kNQ];
#pragma unroll
  for (int i = 0; i < kNCls; ++i) qv[i] = s[i];
#pragma unroll
  for (int i = 0; i < kNCls; ++i)
    qv[kNCls + i] = (float)((unsigned)(pack >> (5 * i)) & 31u);
  qv[2 * kNCls] = ss;

  __shared__ float arr[kNQ][kThreads];
#pragma unroll
  for (int q = 0; q < kNQ; ++q) arr[q][tid] = qv[q];
  __syncthreads();

  if (tid < kNQ * 8) {
    const int q = tid >> 3, l = tid & 7;  // 8 lanes per quantity
    const float4* row = reinterpret_cast<const float4*>(arr[q]);
    double dv = 0.0;
#pragma unroll
    for (int jj = 0; jj < kThreads / 32; ++jj) {  // 8 x float4 per lane
      const float4 v = row[l + 8 * jj];
      dv += (double)((v.x + v.y) + (v.z + v.w));
    }
#pragma unroll
    for (int o = 4; o > 0; o >>= 1) dv += __shfl_down(dv, o, 8);
    if (l == 0) pd[(size_t)q * kBlocks + bid] = dv;  // quantity-major
  }
}

__global__ __launch_bounds__(1024) void seg_final_kernel(
    const double* __restrict__ pd, float* __restrict__ out) {
  __shared__ double tot[kNQ];
  const int q = threadIdx.x >> 5;         // 32 lanes per quantity
  const int lane = threadIdx.x & 31;
  if (q < kNQ) {
    double v = 0.0;
#pragma unroll
    for (int j = 0; j < kBlocks / 32; ++j)   // 32 unrolled independent loads
      v += pd[(size_t)q * kBlocks + lane + 32 * j];
#pragma unroll
    for (int o = 16; o > 0; o >>= 1) v += __shfl_down(v, o, 32);
    if (lane == 0) tot[q] = v;
  }
  __syncthreads();
  if (threadIdx.x == 0) {
    const double N = (double)kNPix;
    double acc = tot[2 * kNCls];          // SS_total
    for (int i = 0; i < kNCls; ++i) {
      const double S = tot[i];
      const double C = tot[kNCls + i];
      acc += S * S * (C / N - 2.0) / N;   // -2 S^2/N + C S^2/N^2
    }
    out[0] = (float)(acc / N);
  }
}

extern "C" void kernel_launch(void* const* d_in, const int* in_sizes, int n_in,
                              void* d_out, int out_size, void* d_ws, size_t ws_size,
                              hipStream_t stream) {
  const float* x = (const float*)d_in[0];
  const int* y = (const int*)d_in[1];
  float* out = (float*)d_out;
  double* pd = (double*)d_ws;             // 23 * 1024 * 8 = 188 KB

  seg_main_kernel<<<kBlocks, kThreads, 0, stream>>>(x, y, pd);
  seg_final_kernel<<<1, 1024, 0, stream>>>(pd, out);
}